// Round 3
// baseline (469.861 us; speedup 1.0000x reference)
//
#include <hip/hip_runtime.h>

#define F_IN 128
#define RDIM 128
#define KTOT 384   // 2*F_IN + RDIM
#define ALPHA 0.2f

// ---------- K0: w_i = a_i^T @ a_2  (three 128-vectors) ----------
__global__ __launch_bounds__(128) void k_wvec(const float* __restrict__ a,
                                              const float* __restrict__ a2,
                                              float* __restrict__ w1,
                                              float* __restrict__ w2,
                                              float* __restrict__ w3) {
  int k = threadIdx.x;  // 0..127
  float acc1 = 0.f, acc2 = 0.f, acc3 = 0.f;
  for (int f = 0; f < 128; ++f) {
    float s = a2[f];
    const float* row = a + (size_t)f * KTOT;
    acc1 += s * row[k];
    acc2 += s * row[128 + k];
    acc3 += s * row[256 + k];
  }
  w1[k] = acc1; w2[k] = acc2; w3[k] = acc3;
}

// ---------- K1: s1[n] = input[n]·w1, s2[n] = input[n]·w2 ----------
__global__ __launch_bounds__(256) void k_svec(const float* __restrict__ input,
                                              const float* __restrict__ w1,
                                              const float* __restrict__ w2,
                                              float* __restrict__ s1,
                                              float* __restrict__ s2, int N) {
  int lane = threadIdx.x & 63;
  int n = blockIdx.x * 4 + (threadIdx.x >> 6);
  if (n >= N) return;
  float2 x  = *(const float2*)(input + (size_t)n * F_IN + 2 * lane);
  float2 wa = *(const float2*)(w1 + 2 * lane);
  float2 wb = *(const float2*)(w2 + 2 * lane);
  float p1 = x.x * wa.x + x.y * wa.y;
  float p2 = x.x * wb.x + x.y * wb.y;
  #pragma unroll
  for (int m = 1; m < 64; m <<= 1) {
    p1 += __shfl_xor(p1, m, 64);
    p2 += __shfl_xor(p2, m, 64);
  }
  if (lane == 0) { s1[n] = p1; s2[n] = p2; }
}

// ---------- CSR build (edge rows int32: edge[0..E-1]=src, edge[E..2E-1]=dst) ----------
__global__ __launch_bounds__(256) void k_hist(const int* __restrict__ edge_src,
                                              int* __restrict__ counts, int E) {
  int e = blockIdx.x * 256 + threadIdx.x;
  if (e < E) atomicAdd(&counts[edge_src[e]], 1);
}

__global__ __launch_bounds__(1024) void k_scan(const int* __restrict__ counts,
                                               int* __restrict__ row_ptr,
                                               int* __restrict__ cursor, int N) {
  __shared__ int part[1024];
  int t = threadIdx.x;
  int per = (N + 1023) / 1024;
  int b = t * per;
  int e = b + per; if (e > N) e = N;
  int s = 0;
  for (int i = b; i < e; ++i) s += counts[i];
  part[t] = s;
  __syncthreads();
  for (int off = 1; off < 1024; off <<= 1) {
    int v = (t >= off) ? part[t - off] : 0;
    __syncthreads();
    part[t] += v;
    __syncthreads();
  }
  int run = part[t] - s;  // exclusive base for this chunk
  for (int i = b; i < e; ++i) { row_ptr[i] = run; cursor[i] = run; run += counts[i]; }
  if (t == 1023) row_ptr[N] = part[1023];
}

// fused CSR payload: csr_e (edge id), csr_d (dst), csr_s (s2[dst])
__global__ __launch_bounds__(256) void k_scatter(const int* __restrict__ edge_src,
                                                 const int* __restrict__ edge_dst,
                                                 const float* __restrict__ s2,
                                                 int* __restrict__ cursor,
                                                 int* __restrict__ csr_e,
                                                 int* __restrict__ csr_d,
                                                 float* __restrict__ csr_s, int E) {
  int e = blockIdx.x * 256 + threadIdx.x;
  if (e >= E) return;
  int src = edge_src[e];
  int dst = edge_dst[e];
  float sv = s2[dst];
  int pos = atomicAdd(&cursor[src], 1);
  csr_e[pos] = e;
  csr_d[pos] = dst;
  csr_s[pos] = sv;
}

// ---------- K3: per-node wave, depth-2 software-pipelined segment reduction ----------
// G[n] = [ (Σ ee*input[dst])/rs | (Σ ee*edge_embed[e])/rs ]  (256 floats)
__global__ __launch_bounds__(256) void k_edge(const float* __restrict__ input,
                                              const float* __restrict__ emb,
                                              const float* __restrict__ w3,
                                              const float* __restrict__ s1,
                                              const int* __restrict__ row_ptr,
                                              const int* __restrict__ csr_e,
                                              const int* __restrict__ csr_d,
                                              const float* __restrict__ csr_s,
                                              float* __restrict__ G,
                                              float* __restrict__ rs, int N) {
  int lane = threadIdx.x & 63;
  int n = blockIdx.x * 4 + (threadIdx.x >> 6);
  if (n >= N) return;
  int beg = row_ptr[n], end = row_ptr[n + 1];
  float2 w3v = *(const float2*)(w3 + 2 * lane);
  float s1n = s1[n];
  float gix = 0.f, giy = 0.f, gex = 0.f, gey = 0.f, rsum = 0.f;

  // pipeline registers: data for i (slot0), data for i+1 (slot1), payload idx for i+2
  float2 x0 = make_float2(0.f, 0.f), y0 = x0, x1 = x0, y1 = x0;
  float sv0 = 0.f, sv1 = 0.f;
  int eN = 0, dN = 0; float svN = 0.f;
  if (beg < end) {
    int e = csr_e[beg], d = csr_d[beg]; sv0 = csr_s[beg];
    x0 = *(const float2*)(emb + (size_t)e * RDIM + 2 * lane);
    y0 = *(const float2*)(input + (size_t)d * F_IN + 2 * lane);
  }
  if (beg + 1 < end) {
    int e = csr_e[beg + 1], d = csr_d[beg + 1]; sv1 = csr_s[beg + 1];
    x1 = *(const float2*)(emb + (size_t)e * RDIM + 2 * lane);
    y1 = *(const float2*)(input + (size_t)d * F_IN + 2 * lane);
  }
  if (beg + 2 < end) { eN = csr_e[beg + 2]; dN = csr_d[beg + 2]; svN = csr_s[beg + 2]; }

  for (int i = beg; i < end; ++i) {
    // issue data loads for i+2 (addresses already in registers — no wait)
    float2 xn = make_float2(0.f, 0.f), yn = xn;
    float svc = svN;
    if (i + 2 < end) {
      xn = *(const float2*)(emb + (size_t)eN * RDIM + 2 * lane);
      yn = *(const float2*)(input + (size_t)dN * F_IN + 2 * lane);
    }
    // issue payload loads for i+3 (consumed next iteration)
    if (i + 3 < end) { eN = csr_e[i + 3]; dN = csr_d[i + 3]; svN = csr_s[i + 3]; }
    // compute on slot0 (loaded two iterations ago)
    float q = x0.x * w3v.x + x0.y * w3v.y;
    #pragma unroll
    for (int m = 1; m < 64; m <<= 1) q += __shfl_xor(q, m, 64);
    float s = s1n + sv0 + q;
    float lr = s > 0.f ? s : ALPHA * s;
    float ee = __expf(-lr);
    rsum += ee;
    gix += ee * y0.x; giy += ee * y0.y;
    gex += ee * x0.x; gey += ee * x0.y;
    // rotate pipeline
    x0 = x1; y0 = y1; sv0 = sv1;
    x1 = xn; y1 = yn; sv1 = svc;
  }

  float scale = rsum > 0.f ? 1.f / rsum : 0.f;
  float* Gn = G + (size_t)n * 256;
  float2 o;
  o.x = gix * scale; o.y = giy * scale;
  *(float2*)(Gn + 2 * lane) = o;
  o.x = gex * scale; o.y = gey * scale;
  *(float2*)(Gn + 128 + 2 * lane) = o;
  if (lane == 0) rs[n] = rsum;
}

// ---------- K4: out = elu( [input | G] @ a^T ), zero rows where rs==0 ----------
__global__ __launch_bounds__(256) void k_out(const float* __restrict__ input,
                                             const float* __restrict__ G,
                                             const float* __restrict__ a,
                                             const float* __restrict__ rs,
                                             float* __restrict__ out, int N) {
  __shared__ float Xs[32][132];   // k-major, padded
  __shared__ float As[32][132];
  int t = threadIdx.x;
  int n0 = blockIdx.x * 128;
  int tx = t & 15, ty = t >> 4;   // 16 feat-groups x 16 node-groups (8 each)
  int r0 = t >> 3, c = t & 7;     // staging map
  float acc[8][8];
  #pragma unroll
  for (int i = 0; i < 8; ++i)
    #pragma unroll
    for (int j = 0; j < 8; ++j) acc[i][j] = 0.f;

  for (int k0 = 0; k0 < KTOT; k0 += 32) {
    #pragma unroll
    for (int pass = 0; pass < 4; ++pass) {
      int r = r0 + pass * 32;   // 0..127
      int n = n0 + r;
      float4 v = make_float4(0.f, 0.f, 0.f, 0.f);
      if (n < N) {
        if (k0 < 128) v = *(const float4*)(input + (size_t)n * 128 + k0 + 4 * c);
        else          v = *(const float4*)(G + (size_t)n * 256 + (k0 - 128) + 4 * c);
      }
      Xs[4 * c + 0][r] = v.x; Xs[4 * c + 1][r] = v.y;
      Xs[4 * c + 2][r] = v.z; Xs[4 * c + 3][r] = v.w;
      float4 w = *(const float4*)(a + (size_t)r * KTOT + k0 + 4 * c);
      As[4 * c + 0][r] = w.x; As[4 * c + 1][r] = w.y;
      As[4 * c + 2][r] = w.z; As[4 * c + 3][r] = w.w;
    }
    __syncthreads();
    #pragma unroll 4
    for (int kk = 0; kk < 32; ++kk) {
      float4 a0 = *(const float4*)&As[kk][8 * tx];
      float4 a1 = *(const float4*)&As[kk][8 * tx + 4];
      float4 x0 = *(const float4*)&Xs[kk][8 * ty];
      float4 x1 = *(const float4*)&Xs[kk][8 * ty + 4];
      float av[8] = {a0.x, a0.y, a0.z, a0.w, a1.x, a1.y, a1.z, a1.w};
      float xv[8] = {x0.x, x0.y, x0.z, x0.w, x1.x, x1.y, x1.z, x1.w};
      #pragma unroll
      for (int i = 0; i < 8; ++i)
        #pragma unroll
        for (int j = 0; j < 8; ++j) acc[i][j] += xv[i] * av[j];
    }
    __syncthreads();
  }
  #pragma unroll
  for (int i = 0; i < 8; ++i) {
    int n = n0 + 8 * ty + i;
    if (n >= N) continue;
    float rsv = rs[n];
    float o[8];
    #pragma unroll
    for (int j = 0; j < 8; ++j) {
      float v = acc[i][j];
      float h = v > 0.f ? v : (__expf(v) - 1.f);
      o[j] = (rsv == 0.f) ? 0.f : h;
    }
    float4* dstp = (float4*)(out + (size_t)n * 128 + 8 * tx);
    dstp[0] = make_float4(o[0], o[1], o[2], o[3]);
    dstp[1] = make_float4(o[4], o[5], o[6], o[7]);
  }
}

extern "C" void kernel_launch(void* const* d_in, const int* in_sizes, int n_in,
                              void* d_out, int out_size, void* d_ws, size_t ws_size,
                              hipStream_t stream) {
  const float* input      = (const float*)d_in[0];
  const int*   edge       = (const int*)d_in[1];   // int32 [2,E] row-major
  const float* edge_embed = (const float*)d_in[2];
  const float* a          = (const float*)d_in[3];
  const float* a_2        = (const float*)d_in[4];
  float* out = (float*)d_out;
  int N = in_sizes[0] / F_IN;
  int E = in_sizes[1] / 2;
  const int* edge_src = edge;
  const int* edge_dst = edge + E;

  char* p = (char*)d_ws;
  auto take = [&](size_t bytes) { char* q = p; p += (bytes + 255) & ~(size_t)255; return q; };
  float* w1      = (float*)take(128 * 4);
  float* w2      = (float*)take(128 * 4);
  float* w3      = (float*)take(128 * 4);
  float* s1      = (float*)take((size_t)N * 4);
  float* s2      = (float*)take((size_t)N * 4);
  float* rs      = (float*)take((size_t)N * 4);
  int*   counts  = (int*)take((size_t)N * 4);
  int*   cursor  = (int*)take((size_t)N * 4);
  int*   row_ptr = (int*)take((size_t)(N + 1) * 4);
  int*   csr_e   = (int*)take((size_t)E * 4);
  int*   csr_d   = (int*)take((size_t)E * 4);
  float* csr_s   = (float*)take((size_t)E * 4);
  float* G       = (float*)take((size_t)N * 256 * 4);

  hipMemsetAsync(counts, 0, (size_t)N * 4, stream);
  k_wvec<<<1, 128, 0, stream>>>(a, a_2, w1, w2, w3);
  k_svec<<<(N + 3) / 4, 256, 0, stream>>>(input, w1, w2, s1, s2, N);
  k_hist<<<(E + 255) / 256, 256, 0, stream>>>(edge_src, counts, E);
  k_scan<<<1, 1024, 0, stream>>>(counts, row_ptr, cursor, N);
  k_scatter<<<(E + 255) / 256, 256, 0, stream>>>(edge_src, edge_dst, s2, cursor,
                                                 csr_e, csr_d, csr_s, E);
  k_edge<<<(N + 3) / 4, 256, 0, stream>>>(input, edge_embed, w3, s1,
                                          row_ptr, csr_e, csr_d, csr_s, G, rs, N);
  k_out<<<(N + 127) / 128, 256, 0, stream>>>(input, G, a, rs, out, N);
}

// Round 4
// 426.857 us; speedup vs baseline: 1.1007x; 1.1007x over previous
//
#include <hip/hip_runtime.h>

#define F_IN 128
#define RDIM 128
#define KTOT 384   // 2*F_IN + RDIM
#define ALPHA 0.2f

// ---------- K0: W[j] = sum_f a2[f]*a[f][j], j in [0,384) ; w1=W[0:128] w2=W[128:256] w3=W[256:384]
__global__ __launch_bounds__(384) void k_wvec(const float* __restrict__ a,
                                              const float* __restrict__ a2,
                                              float* __restrict__ w) {
  int j = threadIdx.x;  // 0..383
  float acc = 0.f;
  for (int f = 0; f < 128; ++f) acc += a2[f] * a[(size_t)f * KTOT + j];
  w[j] = acc;
}

// ---------- K1: s1[n] = input[n]·w1, s2[n] = input[n]·w2 ----------
__global__ __launch_bounds__(256) void k_svec(const float* __restrict__ input,
                                              const float* __restrict__ w1,
                                              const float* __restrict__ w2,
                                              float* __restrict__ s1,
                                              float* __restrict__ s2, int N) {
  int lane = threadIdx.x & 63;
  int n = blockIdx.x * 4 + (threadIdx.x >> 6);
  if (n >= N) return;
  float2 x  = *(const float2*)(input + (size_t)n * F_IN + 2 * lane);
  float2 wa = *(const float2*)(w1 + 2 * lane);
  float2 wb = *(const float2*)(w2 + 2 * lane);
  float p1 = x.x * wa.x + x.y * wa.y;
  float p2 = x.x * wb.x + x.y * wb.y;
  #pragma unroll
  for (int m = 1; m < 64; m <<= 1) {
    p1 += __shfl_xor(p1, m, 64);
    p2 += __shfl_xor(p2, m, 64);
  }
  if (lane == 0) { s1[n] = p1; s2[n] = p2; }
}

// ---------- CSR build (edge rows int32: edge[0..E-1]=src, edge[E..2E-1]=dst) ----------
__global__ __launch_bounds__(256) void k_hist(const int* __restrict__ edge_src,
                                              int* __restrict__ counts, int E) {
  int e = blockIdx.x * 256 + threadIdx.x;
  if (e < E) atomicAdd(&counts[edge_src[e]], 1);
}

__global__ __launch_bounds__(1024) void k_scan(const int* __restrict__ counts,
                                               int* __restrict__ row_ptr,
                                               int* __restrict__ cursor, int N) {
  __shared__ int part[1024];
  int t = threadIdx.x;
  int per = (N + 1023) / 1024;
  int b = t * per;
  int e = b + per; if (e > N) e = N;
  int s = 0;
  for (int i = b; i < e; ++i) s += counts[i];
  part[t] = s;
  __syncthreads();
  for (int off = 1; off < 1024; off <<= 1) {
    int v = (t >= off) ? part[t - off] : 0;
    __syncthreads();
    part[t] += v;
    __syncthreads();
  }
  int run = part[t] - s;  // exclusive base for this chunk
  for (int i = b; i < e; ++i) { row_ptr[i] = run; cursor[i] = run; run += counts[i]; }
  if (t == 1023) row_ptr[N] = part[1023];
}

// fused CSR payload: one int4 {edge id, dst, bitcast(s2[dst]), 0} per slot
__global__ __launch_bounds__(256) void k_scatter(const int* __restrict__ edge_src,
                                                 const int* __restrict__ edge_dst,
                                                 const float* __restrict__ s2,
                                                 int* __restrict__ cursor,
                                                 int4* __restrict__ csr_pack, int E) {
  int e = blockIdx.x * 256 + threadIdx.x;
  if (e >= E) return;
  int src = edge_src[e];
  int dst = edge_dst[e];
  float sv = s2[dst];
  int pos = atomicAdd(&cursor[src], 1);
  csr_pack[pos] = make_int4(e, dst, __float_as_int(sv), 0);
}

// ---------- K3: per-node wave; 2 edges per iteration (32 lanes each), depth-2 pipeline ----
// G[n] = [ (Σ ee*input[dst])/rs | (Σ ee*edge_embed[e])/rs ]  (256 floats)
__global__ __launch_bounds__(256) void k_edge(const float* __restrict__ input,
                                              const float* __restrict__ emb,
                                              const float* __restrict__ w3,
                                              const float* __restrict__ s1,
                                              const int* __restrict__ row_ptr,
                                              const int4* __restrict__ csr_pack,
                                              float* __restrict__ G,
                                              float* __restrict__ rs, int N) {
  int lane = threadIdx.x & 63;
  int h = lane >> 5;     // which edge of the pair this lane serves
  int c = lane & 31;     // feature sublane: features 4c..4c+3
  int n = blockIdx.x * 4 + (threadIdx.x >> 6);
  if (n >= N) return;
  int beg = row_ptr[n], end = row_ptr[n + 1];
  float4 w3v = *(const float4*)(w3 + 4 * c);
  float s1n = s1[n];
  float4 gi = make_float4(0.f, 0.f, 0.f, 0.f), ge = gi;
  float rsum = 0.f;

  float4 z4 = make_float4(0.f, 0.f, 0.f, 0.f);
  float4 x0 = z4, y0 = z4, x1 = z4, y1 = z4;
  float sv0 = 0.f, sv1 = 0.f;
  bool va0 = false, va1 = false;
  int4 pN = make_int4(0, 0, 0, 0);

  int i0 = beg + h;  // this lane-half's slot-0 edge index
  if (i0 < end) {
    int4 p = csr_pack[i0];
    sv0 = __int_as_float(p.z);
    x0 = *(const float4*)(emb + (size_t)p.x * RDIM + 4 * c);
    y0 = *(const float4*)(input + (size_t)p.y * F_IN + 4 * c);
    va0 = true;
  }
  if (i0 + 2 < end) {
    int4 p = csr_pack[i0 + 2];
    sv1 = __int_as_float(p.z);
    x1 = *(const float4*)(emb + (size_t)p.x * RDIM + 4 * c);
    y1 = *(const float4*)(input + (size_t)p.y * F_IN + 4 * c);
    va1 = true;
  }
  if (i0 + 4 < end) pN = csr_pack[i0 + 4];

  for (int i = beg; i < end; i += 2) {
    // prefetch data for edges (i+4, i+5) from payload loaded last iteration
    float4 xn = z4, yn = z4;
    float svn = __int_as_float(pN.z);
    bool vn = (i + 4 + h) < end;
    if (vn) {
      xn = *(const float4*)(emb + (size_t)pN.x * RDIM + 4 * c);
      yn = *(const float4*)(input + (size_t)pN.y * F_IN + 4 * c);
    }
    // prefetch payload for edges (i+6, i+7)
    if (i + 6 + h < end) pN = csr_pack[i + 6 + h];
    // compute on slot 0 (edges i, i+1)
    float q = x0.x * w3v.x + x0.y * w3v.y + x0.z * w3v.z + x0.w * w3v.w;
    #pragma unroll
    for (int m = 1; m < 32; m <<= 1) q += __shfl_xor(q, m, 64);  // within-half reduce
    float s = s1n + sv0 + q;
    float lr = s > 0.f ? s : ALPHA * s;
    float ee = va0 ? __expf(-lr) : 0.f;
    rsum += ee;
    gi.x += ee * y0.x; gi.y += ee * y0.y; gi.z += ee * y0.z; gi.w += ee * y0.w;
    ge.x += ee * x0.x; ge.y += ee * x0.y; ge.z += ee * x0.z; ge.w += ee * x0.w;
    // rotate pipeline
    x0 = x1; y0 = y1; sv0 = sv1; va0 = va1;
    x1 = xn; y1 = yn; sv1 = svn; va1 = vn;
  }

  // merge the two halves (each covered half the edges, same features)
  rsum += __shfl_xor(rsum, 32, 64);
  gi.x += __shfl_xor(gi.x, 32, 64); gi.y += __shfl_xor(gi.y, 32, 64);
  gi.z += __shfl_xor(gi.z, 32, 64); gi.w += __shfl_xor(gi.w, 32, 64);
  ge.x += __shfl_xor(ge.x, 32, 64); ge.y += __shfl_xor(ge.y, 32, 64);
  ge.z += __shfl_xor(ge.z, 32, 64); ge.w += __shfl_xor(ge.w, 32, 64);

  float scale = rsum > 0.f ? 1.f / rsum : 0.f;
  if (h == 0) {
    float* Gn = G + (size_t)n * 256;
    *(float4*)(Gn + 4 * c)       = make_float4(gi.x * scale, gi.y * scale, gi.z * scale, gi.w * scale);
    *(float4*)(Gn + 128 + 4 * c) = make_float4(ge.x * scale, ge.y * scale, ge.z * scale, ge.w * scale);
  }
  if (lane == 0) rs[n] = rsum;
}

// ---------- K4: out = elu( [input | G] @ a^T ), zero rows where rs==0 ----------
__global__ __launch_bounds__(256) void k_out(const float* __restrict__ input,
                                             const float* __restrict__ G,
                                             const float* __restrict__ a,
                                             const float* __restrict__ rs,
                                             float* __restrict__ out, int N) {
  __shared__ float Xs[32][132];   // k-major, padded
  __shared__ float As[32][132];
  int t = threadIdx.x;
  int n0 = blockIdx.x * 128;
  int tx = t & 15, ty = t >> 4;   // 16 feat-groups x 16 node-groups (8 each)
  int r0 = t >> 3, c = t & 7;     // staging map
  float acc[8][8];
  #pragma unroll
  for (int i = 0; i < 8; ++i)
    #pragma unroll
    for (int j = 0; j < 8; ++j) acc[i][j] = 0.f;

  for (int k0 = 0; k0 < KTOT; k0 += 32) {
    #pragma unroll
    for (int pass = 0; pass < 4; ++pass) {
      int r = r0 + pass * 32;   // 0..127
      int n = n0 + r;
      float4 v = make_float4(0.f, 0.f, 0.f, 0.f);
      if (n < N) {
        if (k0 < 128) v = *(const float4*)(input + (size_t)n * 128 + k0 + 4 * c);
        else          v = *(const float4*)(G + (size_t)n * 256 + (k0 - 128) + 4 * c);
      }
      Xs[4 * c + 0][r] = v.x; Xs[4 * c + 1][r] = v.y;
      Xs[4 * c + 2][r] = v.z; Xs[4 * c + 3][r] = v.w;
      float4 w = *(const float4*)(a + (size_t)r * KTOT + k0 + 4 * c);
      As[4 * c + 0][r] = w.x; As[4 * c + 1][r] = w.y;
      As[4 * c + 2][r] = w.z; As[4 * c + 3][r] = w.w;
    }
    __syncthreads();
    #pragma unroll 4
    for (int kk = 0; kk < 32; ++kk) {
      float4 a0 = *(const float4*)&As[kk][8 * tx];
      float4 a1 = *(const float4*)&As[kk][8 * tx + 4];
      float4 x0 = *(const float4*)&Xs[kk][8 * ty];
      float4 x1 = *(const float4*)&Xs[kk][8 * ty + 4];
      float av[8] = {a0.x, a0.y, a0.z, a0.w, a1.x, a1.y, a1.z, a1.w};
      float xv[8] = {x0.x, x0.y, x0.z, x0.w, x1.x, x1.y, x1.z, x1.w};
      #pragma unroll
      for (int i = 0; i < 8; ++i)
        #pragma unroll
        for (int j = 0; j < 8; ++j) acc[i][j] += xv[i] * av[j];
    }
    __syncthreads();
  }
  #pragma unroll
  for (int i = 0; i < 8; ++i) {
    int n = n0 + 8 * ty + i;
    if (n >= N) continue;
    float rsv = rs[n];
    float o[8];
    #pragma unroll
    for (int j = 0; j < 8; ++j) {
      float v = acc[i][j];
      float h = v > 0.f ? v : (__expf(v) - 1.f);
      o[j] = (rsv == 0.f) ? 0.f : h;
    }
    float4* dstp = (float4*)(out + (size_t)n * 128 + 8 * tx);
    dstp[0] = make_float4(o[0], o[1], o[2], o[3]);
    dstp[1] = make_float4(o[4], o[5], o[6], o[7]);
  }
}

extern "C" void kernel_launch(void* const* d_in, const int* in_sizes, int n_in,
                              void* d_out, int out_size, void* d_ws, size_t ws_size,
                              hipStream_t stream) {
  const float* input      = (const float*)d_in[0];
  const int*   edge       = (const int*)d_in[1];   // int32 [2,E] row-major
  const float* edge_embed = (const float*)d_in[2];
  const float* a          = (const float*)d_in[3];
  const float* a_2        = (const float*)d_in[4];
  float* out = (float*)d_out;
  int N = in_sizes[0] / F_IN;
  int E = in_sizes[1] / 2;
  const int* edge_src = edge;
  const int* edge_dst = edge + E;

  char* p = (char*)d_ws;
  auto take = [&](size_t bytes) { char* q = p; p += (bytes + 255) & ~(size_t)255; return q; };
  float* w        = (float*)take(KTOT * 4);        // w1|w2|w3 contiguous
  float* s1       = (float*)take((size_t)N * 4);
  float* s2       = (float*)take((size_t)N * 4);
  float* rs       = (float*)take((size_t)N * 4);
  int*   counts   = (int*)take((size_t)N * 4);
  int*   cursor   = (int*)take((size_t)N * 4);
  int*   row_ptr  = (int*)take((size_t)(N + 1) * 4);
  int4*  csr_pack = (int4*)take((size_t)E * 16);
  float* G        = (float*)take((size_t)N * 256 * 4);

  hipMemsetAsync(counts, 0, (size_t)N * 4, stream);
  k_wvec<<<1, 384, 0, stream>>>(a, a_2, w);
  k_svec<<<(N + 3) / 4, 256, 0, stream>>>(input, w, w + 128, s1, s2, N);
  k_hist<<<(E + 255) / 256, 256, 0, stream>>>(edge_src, counts, E);
  k_scan<<<1, 1024, 0, stream>>>(counts, row_ptr, cursor, N);
  k_scatter<<<(E + 255) / 256, 256, 0, stream>>>(edge_src, edge_dst, s2, cursor,
                                                 csr_pack, E);
  k_edge<<<(N + 3) / 4, 256, 0, stream>>>(input, edge_embed, w + 256, s1,
                                          row_ptr, csr_pack, G, rs, N);
  k_out<<<(N + 127) / 128, 256, 0, stream>>>(input, G, a, rs, out, N);
}

// Round 6
// 372.669 us; speedup vs baseline: 1.2608x; 1.1454x over previous
//
#include <hip/hip_runtime.h>

#define F_IN 128
#define RDIM 128
#define KTOT 384   // 2*F_IN + RDIM
#define ALPHA 0.2f

typedef short bf8 __attribute__((ext_vector_type(8)));   // 8 bf16 = 4 VGPRs
typedef float f4 __attribute__((ext_vector_type(4)));
typedef float fv4 __attribute__((ext_vector_type(4)));   // plain-vec float4 (nt-capable)
typedef int   iv4 __attribute__((ext_vector_type(4)));   // plain-vec int4   (nt-capable)

__device__ inline unsigned short f2bf(float f) {
  unsigned u = __float_as_uint(f);
  unsigned r = u + 0x7FFFu + ((u >> 16) & 1u);   // round-nearest-even
  return (unsigned short)(r >> 16);
}

// ---------- K_prep: fused {a -> bf16 | zero counts | w = a^T a_2} ----------
// blocks [0,192): convert a (49152 elems); [192,192+zb): zero counts; last 2: w[384]
__global__ __launch_bounds__(256) void k_prep(const float* __restrict__ a,
                                              const float* __restrict__ a2,
                                              unsigned short* __restrict__ aB,
                                              int* __restrict__ counts,
                                              float* __restrict__ w,
                                              int N, int zb) {
  int b = blockIdx.x, t = threadIdx.x;
  if (b < 192) {
    int i = b * 256 + t;                     // < 49152 always
    aB[i] = f2bf(a[i]);
  } else if (b < 192 + zb) {
    int i = (b - 192) * 256 + t;
    if (i < N) counts[i] = 0;
  } else {
    int j = (b - 192 - zb) * 256 + t;
    if (j < KTOT) {
      float acc = 0.f;
      for (int f = 0; f < 128; ++f) acc += a2[f] * a[(size_t)f * KTOT + j];
      w[j] = acc;
    }
  }
}

// ---------- K1: s1/s2 dot products + input -> bf16 ----------
__global__ __launch_bounds__(256) void k_svec(const float* __restrict__ input,
                                              const float* __restrict__ w1,
                                              const float* __restrict__ w2,
                                              float* __restrict__ s1,
                                              float* __restrict__ s2,
                                              unsigned short* __restrict__ inputB,
                                              int N) {
  int lane = threadIdx.x & 63;
  int n = blockIdx.x * 4 + (threadIdx.x >> 6);
  if (n >= N) return;
  float2 x  = *(const float2*)(input + (size_t)n * F_IN + 2 * lane);
  float2 wa = *(const float2*)(w1 + 2 * lane);
  float2 wb = *(const float2*)(w2 + 2 * lane);
  ushort2 ib; ib.x = f2bf(x.x); ib.y = f2bf(x.y);
  *(ushort2*)(inputB + (size_t)n * F_IN + 2 * lane) = ib;
  float p1 = x.x * wa.x + x.y * wa.y;
  float p2 = x.x * wb.x + x.y * wb.y;
  #pragma unroll
  for (int m = 1; m < 64; m <<= 1) {
    p1 += __shfl_xor(p1, m, 64);
    p2 += __shfl_xor(p2, m, 64);
  }
  if (lane == 0) { s1[n] = p1; s2[n] = p2; }
}

// ---------- CSR build ----------
__global__ __launch_bounds__(256) void k_hist(const int* __restrict__ edge_src,
                                              int* __restrict__ counts, int E) {
  int e = blockIdx.x * 256 + threadIdx.x;
  if (e < E) atomicAdd(&counts[edge_src[e]], 1);
}

__global__ __launch_bounds__(1024) void k_scan(const int* __restrict__ counts,
                                               int* __restrict__ row_ptr,
                                               int* __restrict__ cursor, int N) {
  __shared__ int part[1024];
  int t = threadIdx.x;
  int per = (N + 1023) / 1024;
  int b = t * per;
  int e = b + per; if (e > N) e = N;
  int s = 0;
  for (int i = b; i < e; ++i) s += counts[i];
  part[t] = s;
  __syncthreads();
  for (int off = 1; off < 1024; off <<= 1) {
    int v = (t >= off) ? part[t - off] : 0;
    __syncthreads();
    part[t] += v;
    __syncthreads();
  }
  int run = part[t] - s;
  for (int i = b; i < e; ++i) { row_ptr[i] = run; cursor[i] = run; run += counts[i]; }
  if (t == 1023) row_ptr[N] = part[1023];
}

__global__ __launch_bounds__(256) void k_scatter(const int* __restrict__ edge_src,
                                                 const int* __restrict__ edge_dst,
                                                 const float* __restrict__ s2,
                                                 int* __restrict__ cursor,
                                                 iv4* __restrict__ csr_pack, int E) {
  int e = blockIdx.x * 256 + threadIdx.x;
  if (e >= E) return;
  int src = edge_src[e];
  int dst = edge_dst[e];
  float sv = s2[dst];
  int pos = atomicAdd(&cursor[src], 1);
  iv4 pk; pk.x = e; pk.y = dst; pk.z = __float_as_int(sv); pk.w = 0;
  __builtin_nontemporal_store(pk, &csr_pack[pos]);
}

// ---------- K3: per-node wave; 2 edges/iter; depth-2 pipeline; nt streams; bf16 G ----
__global__ __launch_bounds__(256) void k_edge(const float* __restrict__ input,
                                              const float* __restrict__ emb,
                                              const float* __restrict__ w3,
                                              const float* __restrict__ s1,
                                              const int* __restrict__ row_ptr,
                                              const iv4* __restrict__ csr_pack,
                                              unsigned short* __restrict__ Gb,
                                              float* __restrict__ rs, int N) {
  int lane = threadIdx.x & 63;
  int h = lane >> 5;     // which edge of the pair
  int c = lane & 31;     // feature sublane: features 4c..4c+3
  int n = blockIdx.x * 4 + (threadIdx.x >> 6);
  if (n >= N) return;
  int beg = row_ptr[n], end = row_ptr[n + 1];
  fv4 w3v = *(const fv4*)(w3 + 4 * c);
  float s1n = s1[n];
  fv4 gi = (fv4)(0.f), ge = (fv4)(0.f);
  float rsum = 0.f;

  fv4 z4 = (fv4)(0.f);
  fv4 x0 = z4, y0 = z4, x1 = z4, y1 = z4;
  float sv0 = 0.f, sv1 = 0.f;
  bool va0 = false, va1 = false;
  iv4 pN; pN.x = 0; pN.y = 0; pN.z = 0; pN.w = 0;

  int i0 = beg + h;
  if (i0 < end) {
    iv4 p = __builtin_nontemporal_load(&csr_pack[i0]);
    sv0 = __int_as_float(p.z);
    x0 = __builtin_nontemporal_load((const fv4*)(emb + (size_t)p.x * RDIM + 4 * c));
    y0 = *(const fv4*)(input + (size_t)p.y * F_IN + 4 * c);
    va0 = true;
  }
  if (i0 + 2 < end) {
    iv4 p = __builtin_nontemporal_load(&csr_pack[i0 + 2]);
    sv1 = __int_as_float(p.z);
    x1 = __builtin_nontemporal_load((const fv4*)(emb + (size_t)p.x * RDIM + 4 * c));
    y1 = *(const fv4*)(input + (size_t)p.y * F_IN + 4 * c);
    va1 = true;
  }
  if (i0 + 4 < end) pN = __builtin_nontemporal_load(&csr_pack[i0 + 4]);

  for (int i = beg; i < end; i += 2) {
    fv4 xn = z4, yn = z4;
    float svn = __int_as_float(pN.z);
    bool vn = (i + 4 + h) < end;
    if (vn) {
      xn = __builtin_nontemporal_load((const fv4*)(emb + (size_t)pN.x * RDIM + 4 * c));
      yn = *(const fv4*)(input + (size_t)pN.y * F_IN + 4 * c);
    }
    if (i + 6 + h < end) pN = __builtin_nontemporal_load(&csr_pack[i + 6 + h]);
    // compute on slot 0
    float q = x0.x * w3v.x + x0.y * w3v.y + x0.z * w3v.z + x0.w * w3v.w;
    #pragma unroll
    for (int m = 1; m < 32; m <<= 1) q += __shfl_xor(q, m, 64);  // within-half reduce
    float s = s1n + sv0 + q;
    float lr = s > 0.f ? s : ALPHA * s;
    float ee = va0 ? __expf(-lr) : 0.f;
    rsum += ee;
    gi.x += ee * y0.x; gi.y += ee * y0.y; gi.z += ee * y0.z; gi.w += ee * y0.w;
    ge.x += ee * x0.x; ge.y += ee * x0.y; ge.z += ee * x0.z; ge.w += ee * x0.w;
    x0 = x1; y0 = y1; sv0 = sv1; va0 = va1;
    x1 = xn; y1 = yn; sv1 = svn; va1 = vn;
  }

  rsum += __shfl_xor(rsum, 32, 64);
  gi.x += __shfl_xor(gi.x, 32, 64); gi.y += __shfl_xor(gi.y, 32, 64);
  gi.z += __shfl_xor(gi.z, 32, 64); gi.w += __shfl_xor(gi.w, 32, 64);
  ge.x += __shfl_xor(ge.x, 32, 64); ge.y += __shfl_xor(ge.y, 32, 64);
  ge.z += __shfl_xor(ge.z, 32, 64); ge.w += __shfl_xor(ge.w, 32, 64);

  float scale = rsum > 0.f ? 1.f / rsum : 0.f;
  if (h == 0) {
    unsigned short* Gn = Gb + (size_t)n * 256;
    ushort4 o;
    o.x = f2bf(gi.x * scale); o.y = f2bf(gi.y * scale);
    o.z = f2bf(gi.z * scale); o.w = f2bf(gi.w * scale);
    *(ushort4*)(Gn + 4 * c) = o;
    o.x = f2bf(ge.x * scale); o.y = f2bf(ge.y * scale);
    o.z = f2bf(ge.z * scale); o.w = f2bf(ge.w * scale);
    *(ushort4*)(Gn + 128 + 4 * c) = o;
  }
  if (lane == 0) rs[n] = rsum;
}

// ---------- K4: MFMA bf16 GEMM: out = elu([inputB | Gb] @ aB^T), rs==0 rows -> 0 ----
// A-frag: row=lane&15, k=(lane>>4)*8+j ; B-frag: col=lane&15, same k map
// C/D: col=lane&15, row=(lane>>4)*4+reg  [m89-verified]
__global__ __launch_bounds__(256) void k_out(const unsigned short* __restrict__ inputB,
                                             const unsigned short* __restrict__ Gb,
                                             const unsigned short* __restrict__ aB,
                                             const float* __restrict__ rs,
                                             float* __restrict__ out, int N) {
  int t = threadIdx.x;
  int w = t >> 6, lane = t & 63;
  int lg = lane >> 4, lr = lane & 15;
  int rowbase = blockIdx.x * 128 + w * 32;
  int koff = lg * 8;

  f4 acc[2][8];
  #pragma unroll
  for (int r = 0; r < 2; ++r)
    #pragma unroll
    for (int c = 0; c < 8; ++c) acc[r][c] = (f4)(0.f);

  #pragma unroll
  for (int ks = 0; ks < 12; ++ks) {
    const int k0 = ks * 32;
    bf8 Af[2], Bf[8];
    #pragma unroll
    for (int r = 0; r < 2; ++r) {
      int row = rowbase + r * 16 + lr;
      if (k0 < 128)
        Af[r] = *(const bf8*)(inputB + (size_t)row * 128 + k0 + koff);
      else
        Af[r] = *(const bf8*)(Gb + (size_t)row * 256 + (k0 - 128) + koff);
    }
    #pragma unroll
    for (int c = 0; c < 8; ++c)
      Bf[c] = *(const bf8*)(aB + (size_t)(c * 16 + lr) * KTOT + k0 + koff);
    #pragma unroll
    for (int r = 0; r < 2; ++r)
      #pragma unroll
      for (int c = 0; c < 8; ++c)
        acc[r][c] = __builtin_amdgcn_mfma_f32_16x16x32_bf16(Af[r], Bf[c], acc[r][c], 0, 0, 0);
  }

  #pragma unroll
  for (int r = 0; r < 2; ++r) {
    #pragma unroll
    for (int j = 0; j < 4; ++j) {
      int row = rowbase + r * 16 + lg * 4 + j;
      if (row >= N) continue;
      float rsv = rs[row];
      #pragma unroll
      for (int c = 0; c < 8; ++c) {
        float v = acc[r][c][j];
        float hh = v > 0.f ? v : (__expf(v) - 1.f);
        out[(size_t)row * 128 + c * 16 + lr] = (rsv == 0.f) ? 0.f : hh;
      }
    }
  }
}

extern "C" void kernel_launch(void* const* d_in, const int* in_sizes, int n_in,
                              void* d_out, int out_size, void* d_ws, size_t ws_size,
                              hipStream_t stream) {
  const float* input      = (const float*)d_in[0];
  const int*   edge       = (const int*)d_in[1];   // int32 [2,E] row-major
  const float* edge_embed = (const float*)d_in[2];
  const float* a          = (const float*)d_in[3];
  const float* a_2        = (const float*)d_in[4];
  float* out = (float*)d_out;
  int N = in_sizes[0] / F_IN;
  int E = in_sizes[1] / 2;
  const int* edge_src = edge;
  const int* edge_dst = edge + E;

  char* p = (char*)d_ws;
  auto take = [&](size_t bytes) { char* q = p; p += (bytes + 255) & ~(size_t)255; return q; };
  float* w        = (float*)take(KTOT * 4);        // w1|w2|w3 contiguous
  float* s1       = (float*)take((size_t)N * 4);
  float* s2       = (float*)take((size_t)N * 4);
  float* rs       = (float*)take((size_t)N * 4);
  int*   counts   = (int*)take((size_t)N * 4);
  int*   cursor   = (int*)take((size_t)N * 4);
  int*   row_ptr  = (int*)take((size_t)(N + 1) * 4);
  unsigned short* aB     = (unsigned short*)take((size_t)128 * KTOT * 2);
  unsigned short* inputB = (unsigned short*)take((size_t)N * 128 * 2);
  iv4*  csr_pack = (iv4*)take((size_t)E * 16);
  unsigned short* Gb     = (unsigned short*)take((size_t)N * 256 * 2);
  (void)take(64 * 1024);   // tail pad: k_out overreads <=48 rows past N

  int zb = (N + 255) / 256;
  k_prep<<<192 + zb + 2, 256, 0, stream>>>(a, a_2, aB, counts, w, N, zb);
  k_svec<<<(N + 3) / 4, 256, 0, stream>>>(input, w, w + 128, s1, s2, inputB, N);
  k_hist<<<(E + 255) / 256, 256, 0, stream>>>(edge_src, counts, E);
  k_scan<<<1, 1024, 0, stream>>>(counts, row_ptr, cursor, N);
  k_scatter<<<(E + 255) / 256, 256, 0, stream>>>(edge_src, edge_dst, s2, cursor,
                                                 csr_pack, E);
  k_edge<<<(N + 3) / 4, 256, 0, stream>>>(input, edge_embed, w + 256, s1,
                                          row_ptr, csr_pack, Gb, rs, N);
  k_out<<<(N + 127) / 128, 256, 0, stream>>>(inputB, Gb, aB, rs, out, N);
}